// Round 11
// baseline (986.436 us; speedup 1.0000x reference)
//
#include <hip/hip_runtime.h>
#include <hip/hip_bf16.h>
#include <math.h>

#define TT 512
#define NN 200
#define HH 64
#define EE 16
#define RR 10
#define MU_OFF 0
#define COV_OFF (TT*NN)      // 102400
#define HBLK (NN*NN)         // 40000 floats per t-block of cov
#define HPAD 68              // padded hist row

typedef __bf16 bf16x8 __attribute__((ext_vector_type(8)));
typedef float  f32x4  __attribute__((ext_vector_type(4)));

#define MFMA(a,b,c) __builtin_amdgcn_mfma_f32_16x16x32_bf16(a, b, c, 0, 0, 0)

__device__ __forceinline__ float sigmoidf_(float x) {
    return 1.0f / (1.0f + __expf(-x));
}
__device__ __forceinline__ float tanhf_(float x) {
    x = fminf(15.0f, fmaxf(-15.0f, x));
    float e = __expf(2.0f * x);
    return (e - 1.0f) / (e + 1.0f);
}
// unified gate activation: sigmoid(g) or tanh(g)=2*sigmoid(2g)-1
__device__ __forceinline__ float act_(float g, bool is_tanh) {
    float xx = is_tanh ? 2.0f * g : g;
    float e = __expf(-xx);
    float v = 1.0f / (1.0f + e);
    return is_tanh ? fmaf(2.0f, v, -1.0f) : v;
}

// Raw wave-counted barrier: waits LDS only (lgkmcnt), never drains vmcnt,
// so the periodic global flush stores stay in flight across ticks.
#define BAR() do { asm volatile("s_waitcnt lgkmcnt(0)" ::: "memory"); \
                   __builtin_amdgcn_s_barrier();                      \
                   asm volatile("" ::: "memory"); } while (0)

#define MT4(M) M(0) M(1) M(2) M(3)

// pack two float4 (8 consecutive k) into a bf16x8 fragment
#define PACK8(dst, u0, u1) \
    dst[0]=(__bf16)u0.x; dst[1]=(__bf16)u0.y; dst[2]=(__bf16)u0.z; dst[3]=(__bf16)u0.w; \
    dst[4]=(__bf16)u1.x; dst[5]=(__bf16)u1.y; dst[6]=(__bf16)u1.z; dst[7]=(__bf16)u1.w;

// load 8 consecutive floats from p, convert to a bf16x8 A-fragment
#define LDW(dst, p) { const float4* q4_ = (const float4*)(p); \
    float4 u0_ = q4_[0], u1_ = q4_[1]; PACK8(dst, u0_, u1_) }

// keep a preloaded fragment opaque so the backend cannot re-materialize the
// global loads inside the t-loop
#define PINF(v) asm volatile("" : "+v"(v))

// ---------------- Kernel A: 2-layer LSTM on the MATRIX pipe -----------------
// 512 threads = 8 waves, 1 WG per batch element (grid 200; wall time is
// ticks x per-tick critical path -- R10 proved grid consolidation is useless).
// Waves 0-3: layer0 (step t), wave w owns gate w (rows w*64..w*64+63).
// Waves 4-7: layer1 (step t-1), gate w-4.
// Per wave: 4 M-tiles x {2,4} K-tiles of mfma_f32_16x16x32_bf16.
// A-fragments (weights, bf16) preloaded ONCE: row=lane&15, k=(lane>>4)*8+j.
// B-operand: h broadcast into all 16 cols (col0 read back; no masking).
// D: col=lane&15, row=(lane>>4)*4+reg -> lanes lm==0 hold 4 consecutive rows,
// apply the (wave-uniform) activation there and ds_write_b128 into ga arrays.
// Update phase + skew + hist flush identical to R7. State c,h stays FP32.
__global__
__attribute__((amdgpu_flat_work_group_size(512, 512), amdgpu_waves_per_eu(2, 2)))
void lstm_kernel(
    const float* __restrict__ inputs,
    const float* __restrict__ Wih0, const float* __restrict__ Whh0,
    const float* __restrict__ bih0, const float* __restrict__ bhh0,
    const float* __restrict__ Wih1, const float* __restrict__ Whh1,
    const float* __restrict__ bih1, const float* __restrict__ bhh1,
    float* __restrict__ out)
{
    const int n    = blockIdx.x;
    const int tid  = threadIdx.x;
    const int lane = tid & 63;
    const int lm   = lane & 15;     // MFMA row/col-within-tile index
    const int kg   = lane >> 4;     // MFMA k-group (0..3)
    const int wid  = tid >> 6;      // wave 0..7

    __shared__ float xs[TT];
    __shared__ float h0s[HH], h1s[HH];
    __shared__ float ga0[256], ga1[256];   // ACTIVATED gates
    __shared__ float hist[64][HPAD];       // h1 history, flushed every 64 ticks

    xs[tid] = inputs[tid * NN + n];
    if (tid < HH) { h0s[tid] = 0.0f; h1s[tid] = 0.0f; }

    float* covbase = out + COV_OFF + n * HH;

    if (wid < 4) {
        // ================= layer-0 waves: gate = wid =================
        const int  RB   = wid * 64;
        const bool is_t = (wid == 2);
#define DECL0(mt) \
        bf16x8 aA_##mt, aB_##mt; float4 wx_##mt, bb_##mt; \
        { const float* pw_ = Whh0 + (size_t)(RB + mt*16 + lm) * HH + kg * 8; \
          LDW(aA_##mt, pw_); LDW(aB_##mt, pw_ + 32); \
          PINF(aA_##mt); PINF(aB_##mt); \
          const int er_ = RB + mt*16 + kg*4; \
          wx_##mt = *(const float4*)(Wih0 + er_); \
          float4 b1_ = *(const float4*)(bih0 + er_); \
          float4 b2_ = *(const float4*)(bhh0 + er_); \
          bb_##mt.x = b1_.x + b2_.x; bb_##mt.y = b1_.y + b2_.y; \
          bb_##mt.z = b1_.z + b2_.z; bb_##mt.w = b1_.w + b2_.w; }
        MT4(DECL0)
        float c0 = 0.0f;            // live in lanes of wave 0 (tid<64)

        BAR();  // init

        for (int t = 0; t <= TT; ++t) {
            if (t < TT) {
                const float x = xs[t];
                bf16x8 B0, B1;      // h0[t-1] broadcast into all 16 cols
                { const float4* p_ = (const float4*)(h0s + kg * 8);
                  float4 u0_ = p_[0], u1_ = p_[1]; PACK8(B0, u0_, u1_) }
                { const float4* p_ = (const float4*)(h0s + 32 + kg * 8);
                  float4 u0_ = p_[0], u1_ = p_[1]; PACK8(B1, u0_, u1_) }
#define MM0(mt) { f32x4 d_ = {0.f, 0.f, 0.f, 0.f}; \
                d_ = MFMA(aA_##mt, B0, d_); \
                d_ = MFMA(aB_##mt, B1, d_); \
                float gx_ = act_(d_[0] + fmaf(wx_##mt.x, x, bb_##mt.x), is_t); \
                float gy_ = act_(d_[1] + fmaf(wx_##mt.y, x, bb_##mt.y), is_t); \
                float gz_ = act_(d_[2] + fmaf(wx_##mt.z, x, bb_##mt.z), is_t); \
                float gw_ = act_(d_[3] + fmaf(wx_##mt.w, x, bb_##mt.w), is_t); \
                if (lm == 0) { \
                    float4 g_; g_.x = gx_; g_.y = gy_; g_.z = gz_; g_.w = gw_; \
                    *(float4*)(ga0 + RB + mt*16 + kg*4) = g_; } }
                MT4(MM0)
            }
            BAR();
            if (t < TT && tid < HH) {
                float ia = ga0[tid], fa = ga0[tid + 64];
                float gg = ga0[tid + 128], oa = ga0[tid + 192];
                c0 = fmaf(fa, c0, ia * gg);
                h0s[tid] = oa * tanhf_(c0);
            }
            BAR();
            if ((t & 63) == 0 && t > 0) {   // flush steps t-64..t-1
                const int s  = tid >> 3;
                const int cc = (tid & 7) * 8;
                float4 v0 = *(const float4*)&hist[s][cc];
                float4 v1 = *(const float4*)&hist[s][cc + 4];
                float* dst = covbase + (size_t)(t - 64 + s) * HBLK + cc;
                ((float4*)dst)[0] = v0;
                ((float4*)dst)[1] = v1;
            }
        }
    } else {
        // ================= layer-1 waves: gate = wid-4, step t-1 =======
        const int  RB   = (wid - 4) * 64;
        const bool is_t = (wid == 6);
#define DECL1(mt) \
        bf16x8 aI0_##mt, aI1_##mt, aH0_##mt, aH1_##mt; float4 bb_##mt; \
        { const size_t ro_ = (size_t)(RB + mt*16 + lm) * HH + kg * 8; \
          LDW(aI0_##mt, Wih1 + ro_); LDW(aI1_##mt, Wih1 + ro_ + 32); \
          LDW(aH0_##mt, Whh1 + ro_); LDW(aH1_##mt, Whh1 + ro_ + 32); \
          PINF(aI0_##mt); PINF(aI1_##mt); PINF(aH0_##mt); PINF(aH1_##mt); \
          const int er_ = RB + mt*16 + kg*4; \
          float4 b1_ = *(const float4*)(bih1 + er_); \
          float4 b2_ = *(const float4*)(bhh1 + er_); \
          bb_##mt.x = b1_.x + b2_.x; bb_##mt.y = b1_.y + b2_.y; \
          bb_##mt.z = b1_.z + b2_.z; bb_##mt.w = b1_.w + b2_.w; }
        MT4(DECL1)
        float c1 = 0.0f;            // live in lanes of wave 4 (tid 256..319)

        BAR();  // init

        for (int t = 0; t <= TT; ++t) {
            if (t >= 1) {
                bf16x8 B0, B1, B2, B3;   // [h0[t-1] | h1[t-2]] broadcast
                { const float4* p_ = (const float4*)(h0s + kg * 8);
                  float4 u0_ = p_[0], u1_ = p_[1]; PACK8(B0, u0_, u1_) }
                { const float4* p_ = (const float4*)(h0s + 32 + kg * 8);
                  float4 u0_ = p_[0], u1_ = p_[1]; PACK8(B1, u0_, u1_) }
                { const float4* p_ = (const float4*)(h1s + kg * 8);
                  float4 u0_ = p_[0], u1_ = p_[1]; PACK8(B2, u0_, u1_) }
                { const float4* p_ = (const float4*)(h1s + 32 + kg * 8);
                  float4 u0_ = p_[0], u1_ = p_[1]; PACK8(B3, u0_, u1_) }
#define MM1(mt) { f32x4 d_ = {0.f, 0.f, 0.f, 0.f}; \
                d_ = MFMA(aI0_##mt, B0, d_); \
                d_ = MFMA(aI1_##mt, B1, d_); \
                d_ = MFMA(aH0_##mt, B2, d_); \
                d_ = MFMA(aH1_##mt, B3, d_); \
                float gx_ = act_(d_[0] + bb_##mt.x, is_t); \
                float gy_ = act_(d_[1] + bb_##mt.y, is_t); \
                float gz_ = act_(d_[2] + bb_##mt.z, is_t); \
                float gw_ = act_(d_[3] + bb_##mt.w, is_t); \
                if (lm == 0) { \
                    float4 g_; g_.x = gx_; g_.y = gy_; g_.z = gz_; g_.w = gw_; \
                    *(float4*)(ga1 + RB + mt*16 + kg*4) = g_; } }
                MT4(MM1)
            }
            BAR();
            if (t >= 1 && tid >= 256 && tid < 256 + HH) {
                const int j = tid - 256;
                float ia = ga1[j], fa = ga1[j + 64];
                float gg = ga1[j + 128], oa = ga1[j + 192];
                c1 = fmaf(fa, c1, ia * gg);
                float h1 = oa * tanhf_(c1);
                h1s[j] = h1;
                hist[(t - 1) & 63][j] = h1;
            }
            BAR();
            if ((t & 63) == 0 && t > 0) {   // flush steps t-64..t-1
                const int s  = tid >> 3;
                const int cc = (tid & 7) * 8;
                float4 v0 = *(const float4*)&hist[s][cc];
                float4 v1 = *(const float4*)&hist[s][cc + 4];
                float* dst = covbase + (size_t)(t - 64 + s) * HBLK + cc;
                ((float4*)dst)[0] = v0;
                ((float4*)dst)[1] = v1;
            }
        }
    }
}

// ---------------- Kernel B: heads + covariance, one workgroup per t ----------
__global__ __launch_bounds__(256) void head_kernel(
    const float* __restrict__ embW, const int* __restrict__ indices,
    const float* __restrict__ Wm, const float* __restrict__ bm,
    const float* __restrict__ Wv, const float* __restrict__ bv,
    const float* __restrict__ Wd, const float* __restrict__ bd,
    float* __restrict__ out)
{
    const int t = blockIdx.x;
    const int tid = threadIdx.x;

    __shared__ float hs[NN * HH];          // 12800
    __shared__ float embs[NN * EE];        // 3200
    __shared__ float Wvs[(HH + EE) * RR];  // 800
    __shared__ float Wms[HH + EE];
    __shared__ float Wds[HH + EE];
    __shared__ float Vs[NN * (RR + 1)];    // stride 11 to dodge bank conflicts
    __shared__ float dsh[NN];
    __shared__ float bvs[RR];

    const float* hsrc = out + COV_OFF + (size_t)t * HBLK;
    for (int i = tid; i < (NN * HH) / 4; i += 256)
        ((float4*)hs)[i] = ((const float4*)hsrc)[i];
    for (int i = tid; i < NN * EE; i += 256) {
        int n = i >> 4, e = i & 15;
        embs[i] = embW[indices[n] * EE + e];
    }
    for (int i = tid; i < (HH + EE) * RR; i += 256) Wvs[i] = Wv[i];
    if (tid < HH + EE) { Wms[tid] = Wm[tid]; Wds[tid] = Wd[tid]; }
    if (tid < RR) bvs[tid] = bv[tid];
    __syncthreads();

    // V = y @ Wv + bv
    for (int p = tid; p < NN * RR; p += 256) {
        int n = p / RR, r = p - n * RR;
        const float* hn = hs + n * HH;
        const float* en = embs + n * EE;
        float acc = bvs[r];
#pragma unroll 8
        for (int k = 0; k < HH; ++k) acc = fmaf(hn[k], Wvs[k * RR + r], acc);
#pragma unroll
        for (int k = 0; k < EE; ++k) acc = fmaf(en[k], Wvs[(HH + k) * RR + r], acc);
        Vs[n * (RR + 1) + r] = acc;
    }
    // mu and d
    const float bmv = bm[0], bdv = bd[0];
    for (int n = tid; n < NN; n += 256) {
        const float* hn = hs + n * HH;
        const float* en = embs + n * EE;
        float am = bmv, ad = bdv;
#pragma unroll 8
        for (int k = 0; k < HH; ++k) {
            float h = hn[k];
            am = fmaf(h, Wms[k], am);
            ad = fmaf(h, Wds[k], ad);
        }
#pragma unroll
        for (int k = 0; k < EE; ++k) {
            float e = en[k];
            am = fmaf(e, Wms[HH + k], am);
            ad = fmaf(e, Wds[HH + k], ad);
        }
        out[MU_OFF + t * NN + n] = am;
        dsh[n] = (ad > 20.0f) ? ad : log1pf(__expf(ad));  // softplus
    }
    __syncthreads();

    // cov[t] = V V^T + diag(d)  — overwrites the whole block (incl. stashed h)
    float* covp = out + COV_OFF + (size_t)t * HBLK;
    for (int p = tid; p < NN * NN; p += 256) {
        int n = p / NN, m = p - n * NN;
        const float* vn = Vs + n * (RR + 1);
        const float* vm = Vs + m * (RR + 1);
        float acc = (n == m) ? dsh[n] : 0.0f;
#pragma unroll
        for (int r = 0; r < RR; ++r) acc = fmaf(vn[r], vm[r], acc);
        covp[p] = acc;
    }
}

extern "C" void kernel_launch(void* const* d_in, const int* in_sizes, int n_in,
                              void* d_out, int out_size, void* d_ws, size_t ws_size,
                              hipStream_t stream) {
    const float* inputs  = (const float*)d_in[0];
    const int*   indices = (const int*)d_in[1];
    const float* embW    = (const float*)d_in[2];
    const float* Wih0    = (const float*)d_in[3];
    const float* Whh0    = (const float*)d_in[4];
    const float* bih0    = (const float*)d_in[5];
    const float* bhh0    = (const float*)d_in[6];
    const float* Wih1    = (const float*)d_in[7];
    const float* Whh1    = (const float*)d_in[8];
    const float* bih1    = (const float*)d_in[9];
    const float* bhh1    = (const float*)d_in[10];
    const float* Wm      = (const float*)d_in[11];
    const float* bm      = (const float*)d_in[12];
    const float* Wv      = (const float*)d_in[13];
    const float* bv      = (const float*)d_in[14];
    const float* Wd      = (const float*)d_in[15];
    const float* bd      = (const float*)d_in[16];
    float* out = (float*)d_out;

    lstm_kernel<<<NN, 512, 0, stream>>>(inputs, Wih0, Whh0, bih0, bhh0,
                                        Wih1, Whh1, bih1, bhh1, out);
    head_kernel<<<TT, 256, 0, stream>>>(embW, indices, Wm, bm, Wv, bv, Wd, bd, out);
}

// Round 12
// 454.828 us; speedup vs baseline: 2.1688x; 2.1688x over previous
//
#include <hip/hip_runtime.h>
#include <hip/hip_bf16.h>
#include <math.h>

#define TT 512
#define NN 200
#define HH 64
#define EE 16
#define RR 10
#define MU_OFF 0
#define COV_OFF (TT*NN)      // 102400
#define HBLK (NN*NN)         // 40000 floats per t-block of cov
#define HPAD 68              // padded hist row

__device__ __forceinline__ float sigmoidf_(float x) {
    return 1.0f / (1.0f + __expf(-x));
}
__device__ __forceinline__ float tanhf_(float x) {
    x = fminf(15.0f, fmaxf(-15.0f, x));
    float e = __expf(2.0f * x);
    return (e - 1.0f) / (e + 1.0f);
}
// unified gate activation: sigmoid(g) or tanh(g)=2*sigmoid(2g)-1
__device__ __forceinline__ float act_(float g, bool is_tanh) {
    float xx = is_tanh ? 2.0f * g : g;
    float e = __expf(-xx);
    float v = 1.0f / (1.0f + e);
    return is_tanh ? fmaf(2.0f, v, -1.0f) : v;
}

// quad_perm DPP xor-swaps (VALU pipe, not LDS pipe)
__device__ __forceinline__ float dppxor1(float v) {   // lanes [1,0,3,2]
    return __int_as_float(__builtin_amdgcn_mov_dpp(__float_as_int(v), 0xB1, 0xf, 0xf, true));
}
__device__ __forceinline__ float dppxor2(float v) {   // lanes [2,3,0,1]
    return __int_as_float(__builtin_amdgcn_mov_dpp(__float_as_int(v), 0x4E, 0xf, 0xf, true));
}

// v_dot2_f32_bf16: acc += w.bf16[0]*h.bf16[0] + w.bf16[1]*h.bf16[1]
// (order within the dword cancels as long as w and h are packed identically)
__device__ __forceinline__ void dot2(float& acc, unsigned w, unsigned h) {
    asm("v_dot2_f32_bf16 %0, %1, %2, %0" : "+v"(acc) : "v"(w), "v"(h));
}

// pack two floats into one dword of 2 bf16 (RNE via compiler cast)
__device__ __forceinline__ unsigned pk2(float a, float b) {
    __bf16 x = (__bf16)a, y = (__bf16)b;
    unsigned short ux = __builtin_bit_cast(unsigned short, x);
    unsigned short uy = __builtin_bit_cast(unsigned short, y);
    return (unsigned)ux | ((unsigned)uy << 16);
}
__device__ __forceinline__ unsigned short bfbits(float a) {
    __bf16 x = (__bf16)a;
    return __builtin_bit_cast(unsigned short, x);
}

// Raw wave-counted barrier: waits LDS only (lgkmcnt), never drains vmcnt.
#define BAR() do { asm volatile("s_waitcnt lgkmcnt(0)" ::: "memory"); \
                   __builtin_amdgcn_s_barrier();                      \
                   asm volatile("" ::: "memory"); } while (0)

#define RM4(M) M(0) M(1) M(2) M(3)

// ---------------- Kernel A: 2-layer LSTM, LDS-bf16 weight stream ------------
// Theory: weights were NEVER register-resident (R2-R11); they re-stream from
// scratch/L2 every tick (~196KB fp32/CU/tick = the ~1650cy plateau). Fix:
// stream them from LDS in bf16 (96KB/tick on the dedicated 128B/cy LDS pipe)
// and consume with v_dot2_f32_bf16 (2 MACs/instr, fp32 accum).
// Chassis = R7: 512 thr, waves 0-3 layer0 (step t), waves 4-7 layer1 (t-1),
// quad-split rows/k, DPP reduce, 2 barriers/tick, hist flush every 64 ticks.
// LDS weight layout [slot][tid][16B] -> ds_read_b128 conflict-free.
__global__
__attribute__((amdgpu_flat_work_group_size(512, 512), amdgpu_waves_per_eu(2, 2)))
void lstm_kernel(
    const float* __restrict__ inputs,
    const float* __restrict__ Wih0, const float* __restrict__ Whh0,
    const float* __restrict__ bih0, const float* __restrict__ bhh0,
    const float* __restrict__ Wih1, const float* __restrict__ Whh1,
    const float* __restrict__ bih1, const float* __restrict__ bhh1,
    float* __restrict__ out)
{
    const int n   = blockIdx.x;
    const int tid = threadIdx.x;

    __shared__ uint4 wA[8 * 256];            // 32KB  layer0 Whh0 bf16
    __shared__ uint4 wB[16 * 256];           // 64KB  layer1 Wih1|Whh1 bf16
    __shared__ float xs[TT];                 // 2KB
    __shared__ __align__(16) unsigned short h0b[HH];  // h0 as bf16
    __shared__ __align__(16) unsigned short h1b[HH];  // h1 as bf16
    __shared__ float ga0[256], ga1[256];     // activated gates (fp32)
    __shared__ float hist[64][HPAD];         // h1 history (fp32)

    xs[tid] = inputs[tid * NN + n];
    if (tid < HH) { h0b[tid] = 0; h1b[tid] = 0; }

    float* covbase = out + COV_OFF + n * HH;

    if (tid < 256) {
        // ================= layer-0 branch (waves 0-3) =================
        const int b4 = tid & ~3;        // first of this thread's 4 rows
        const int qr = tid & 3;         // k-quarter (16 values)
        // ---- stage Whh0 rows b4..b4+3, k-slice qr*16, as bf16 into LDS ----
#define STGA(m) { const float* s_ = Whh0 + (b4 + m) * HH + qr * 16; \
        uint4 p0_, p1_; \
        p0_.x = pk2(s_[0], s_[1]);  p0_.y = pk2(s_[2], s_[3]); \
        p0_.z = pk2(s_[4], s_[5]);  p0_.w = pk2(s_[6], s_[7]); \
        p1_.x = pk2(s_[8], s_[9]);  p1_.y = pk2(s_[10], s_[11]); \
        p1_.z = pk2(s_[12], s_[13]); p1_.w = pk2(s_[14], s_[15]); \
        wA[(m * 2 + 0) * 256 + tid] = p0_; \
        wA[(m * 2 + 1) * 256 + tid] = p1_; }
        RM4(STGA)
        const float wx = Wih0[tid];
        const float b0 = bih0[tid] + bhh0[tid];
        const bool is_t = ((tid >> 6) == 2);
        float c0 = 0.0f;

        BAR();  // init (also covers weight staging)

        for (int t = 0; t <= TT; ++t) {
            if (t < TT) {
                const float x = xs[t];
                const uint4* hp = (const uint4*)(h0b + qr * 16);  // qr*32B
                uint4 ha = hp[0], hb = hp[1];
                float acc0, acc1, acc2, acc3;
#define MVA(m) { \
                uint4 wa_ = wA[(m * 2 + 0) * 256 + tid]; \
                uint4 wb_ = wA[(m * 2 + 1) * 256 + tid]; \
                float a_ = 0.0f; \
                dot2(a_, wa_.x, ha.x); dot2(a_, wa_.y, ha.y); \
                dot2(a_, wa_.z, ha.z); dot2(a_, wa_.w, ha.w); \
                dot2(a_, wb_.x, hb.x); dot2(a_, wb_.y, hb.y); \
                dot2(a_, wb_.z, hb.z); dot2(a_, wb_.w, hb.w); \
                acc##m = a_; }
                RM4(MVA)
                acc0 += dppxor1(acc0); acc0 += dppxor2(acc0);
                acc1 += dppxor1(acc1); acc1 += dppxor2(acc1);
                acc2 += dppxor1(acc2); acc2 += dppxor2(acc2);
                acc3 += dppxor1(acc3); acc3 += dppxor2(acc3);
                float g = (qr == 0) ? acc0 : (qr == 1) ? acc1 : (qr == 2) ? acc2 : acc3;
                g += fmaf(wx, x, b0);           // own row == tid
                ga0[tid] = act_(g, is_t);
            }
            BAR();
            if (t < TT && tid < HH) {
                float ia = ga0[tid], fa = ga0[tid + 64];
                float gg = ga0[tid + 128], oa = ga0[tid + 192];
                c0 = fmaf(fa, c0, ia * gg);
                float h0n = oa * tanhf_(c0);
                h0b[tid] = bfbits(h0n);
            }
            BAR();
            if ((t & 63) == 0 && t > 0) {   // flush steps t-64..t-1 (A half)
                const int s  = tid >> 3;
                const int cc = (tid & 7) * 8;
                float4 v0 = *(const float4*)&hist[s][cc];
                float4 v1 = *(const float4*)&hist[s][cc + 4];
                float* dst = covbase + (size_t)(t - 64 + s) * HBLK + cc;
                ((float4*)dst)[0] = v0;
                ((float4*)dst)[1] = v1;
            }
        }
    } else {
        // ================= layer-1 branch (waves 4-7), step t-1 ========
        const int r  = tid - 256;
        const int b4 = r & ~3;
        const int qr = r & 3;
        // ---- stage Wih1 / Whh1 rows b4..b4+3, k-slice qr*16 ----
#define STGB(m) { \
        const float* si_ = Wih1 + (b4 + m) * HH + qr * 16; \
        const float* sh_ = Whh1 + (b4 + m) * HH + qr * 16; \
        uint4 p0_, p1_, p2_, p3_; \
        p0_.x = pk2(si_[0], si_[1]);  p0_.y = pk2(si_[2], si_[3]); \
        p0_.z = pk2(si_[4], si_[5]);  p0_.w = pk2(si_[6], si_[7]); \
        p1_.x = pk2(si_[8], si_[9]);  p1_.y = pk2(si_[10], si_[11]); \
        p1_.z = pk2(si_[12], si_[13]); p1_.w = pk2(si_[14], si_[15]); \
        p2_.x = pk2(sh_[0], sh_[1]);  p2_.y = pk2(sh_[2], sh_[3]); \
        p2_.z = pk2(sh_[4], sh_[5]);  p2_.w = pk2(sh_[6], sh_[7]); \
        p3_.x = pk2(sh_[8], sh_[9]);  p3_.y = pk2(sh_[10], sh_[11]); \
        p3_.z = pk2(sh_[12], sh_[13]); p3_.w = pk2(sh_[14], sh_[15]); \
        wB[(m * 4 + 0) * 256 + r] = p0_; \
        wB[(m * 4 + 1) * 256 + r] = p1_; \
        wB[(m * 4 + 2) * 256 + r] = p2_; \
        wB[(m * 4 + 3) * 256 + r] = p3_; }
        RM4(STGB)
        const float b1 = bih1[r] + bhh1[r];
        const bool is_t = ((r >> 6) == 2);
        float c1 = 0.0f;

        BAR();  // init

        for (int t = 0; t <= TT; ++t) {
            if (t >= 1) {
                int idx = r;
                asm volatile("" : "+v"(idx));   // defeat LICM: keep ds_reads in-loop
                const uint4* hp0 = (const uint4*)(h0b + qr * 16);
                const uint4* hp1 = (const uint4*)(h1b + qr * 16);
                uint4 ha0 = hp0[0], ha1 = hp0[1];
                uint4 hb0 = hp1[0], hb1 = hp1[1];
                float acc0, acc1, acc2, acc3;
#define MVB(m) { \
                uint4 wi0_ = wB[(m * 4 + 0) * 256 + idx]; \
                uint4 wi1_ = wB[(m * 4 + 1) * 256 + idx]; \
                uint4 wh0_ = wB[(m * 4 + 2) * 256 + idx]; \
                uint4 wh1_ = wB[(m * 4 + 3) * 256 + idx]; \
                float a_ = 0.0f; \
                dot2(a_, wi0_.x, ha0.x); dot2(a_, wi0_.y, ha0.y); \
                dot2(a_, wi0_.z, ha0.z); dot2(a_, wi0_.w, ha0.w); \
                dot2(a_, wi1_.x, ha1.x); dot2(a_, wi1_.y, ha1.y); \
                dot2(a_, wi1_.z, ha1.z); dot2(a_, wi1_.w, ha1.w); \
                dot2(a_, wh0_.x, hb0.x); dot2(a_, wh0_.y, hb0.y); \
                dot2(a_, wh0_.z, hb0.z); dot2(a_, wh0_.w, hb0.w); \
                dot2(a_, wh1_.x, hb1.x); dot2(a_, wh1_.y, hb1.y); \
                dot2(a_, wh1_.z, hb1.z); dot2(a_, wh1_.w, hb1.w); \
                acc##m = a_; }
                RM4(MVB)
                acc0 += dppxor1(acc0); acc0 += dppxor2(acc0);
                acc1 += dppxor1(acc1); acc1 += dppxor2(acc1);
                acc2 += dppxor1(acc2); acc2 += dppxor2(acc2);
                acc3 += dppxor1(acc3); acc3 += dppxor2(acc3);
                float g = (qr == 0) ? acc0 : (qr == 1) ? acc1 : (qr == 2) ? acc2 : acc3;
                g += b1;                        // own row == r
                ga1[r] = act_(g, is_t);
            }
            BAR();
            if (t >= 1 && tid < 256 + HH) {     // wave 4, lanes 0-63
                const int j = tid - 256;
                float ia = ga1[j], fa = ga1[j + 64];
                float gg = ga1[j + 128], oa = ga1[j + 192];
                c1 = fmaf(fa, c1, ia * gg);
                float h1 = oa * tanhf_(c1);
                h1b[j] = bfbits(h1);
                hist[(t - 1) & 63][j] = h1;
            }
            BAR();
            if ((t & 63) == 0 && t > 0) {   // flush steps t-64..t-1 (B half)
                const int s  = tid >> 3;
                const int cc = (tid & 7) * 8;
                float4 v0 = *(const float4*)&hist[s][cc];
                float4 v1 = *(const float4*)&hist[s][cc + 4];
                float* dst = covbase + (size_t)(t - 64 + s) * HBLK + cc;
                ((float4*)dst)[0] = v0;
                ((float4*)dst)[1] = v1;
            }
        }
    }
}

// ---------------- Kernel B: heads + covariance, one workgroup per t ----------
__global__ __launch_bounds__(256) void head_kernel(
    const float* __restrict__ embW, const int* __restrict__ indices,
    const float* __restrict__ Wm, const float* __restrict__ bm,
    const float* __restrict__ Wv, const float* __restrict__ bv,
    const float* __restrict__ Wd, const float* __restrict__ bd,
    float* __restrict__ out)
{
    const int t = blockIdx.x;
    const int tid = threadIdx.x;

    __shared__ float hs[NN * HH];          // 12800
    __shared__ float embs[NN * EE];        // 3200
    __shared__ float Wvs[(HH + EE) * RR];  // 800
    __shared__ float Wms[HH + EE];
    __shared__ float Wds[HH + EE];
    __shared__ float Vs[NN * (RR + 1)];    // stride 11 to dodge bank conflicts
    __shared__ float dsh[NN];
    __shared__ float bvs[RR];

    const float* hsrc = out + COV_OFF + (size_t)t * HBLK;
    for (int i = tid; i < (NN * HH) / 4; i += 256)
        ((float4*)hs)[i] = ((const float4*)hsrc)[i];
    for (int i = tid; i < NN * EE; i += 256) {
        int n = i >> 4, e = i & 15;
        embs[i] = embW[indices[n] * EE + e];
    }
    for (int i = tid; i < (HH + EE) * RR; i += 256) Wvs[i] = Wv[i];
    if (tid < HH + EE) { Wms[tid] = Wm[tid]; Wds[tid] = Wd[tid]; }
    if (tid < RR) bvs[tid] = bv[tid];
    __syncthreads();

    // V = y @ Wv + bv
    for (int p = tid; p < NN * RR; p += 256) {
        int n = p / RR, r = p - n * RR;
        const float* hn = hs + n * HH;
        const float* en = embs + n * EE;
        float acc = bvs[r];
#pragma unroll 8
        for (int k = 0; k < HH; ++k) acc = fmaf(hn[k], Wvs[k * RR + r], acc);
#pragma unroll
        for (int k = 0; k < EE; ++k) acc = fmaf(en[k], Wvs[(HH + k) * RR + r], acc);
        Vs[n * (RR + 1) + r] = acc;
    }
    // mu and d
    const float bmv = bm[0], bdv = bd[0];
    for (int n = tid; n < NN; n += 256) {
        const float* hn = hs + n * HH;
        const float* en = embs + n * EE;
        float am = bmv, ad = bdv;
#pragma unroll 8
        for (int k = 0; k < HH; ++k) {
            float h = hn[k];
            am = fmaf(h, Wms[k], am);
            ad = fmaf(h, Wds[k], ad);
        }
#pragma unroll
        for (int k = 0; k < EE; ++k) {
            float e = en[k];
            am = fmaf(e, Wms[HH + k], am);
            ad = fmaf(e, Wds[HH + k], ad);
        }
        out[MU_OFF + t * NN + n] = am;
        dsh[n] = (ad > 20.0f) ? ad : log1pf(__expf(ad));  // softplus
    }
    __syncthreads();

    // cov[t] = V V^T + diag(d)  — overwrites the whole block (incl. stashed h)
    float* covp = out + COV_OFF + (size_t)t * HBLK;
    for (int p = tid; p < NN * NN; p += 256) {
        int n = p / NN, m = p - n * NN;
        const float* vn = Vs + n * (RR + 1);
        const float* vm = Vs + m * (RR + 1);
        float acc = (n == m) ? dsh[n] : 0.0f;
#pragma unroll
        for (int r = 0; r < RR; ++r) acc = fmaf(vn[r], vm[r], acc);
        covp[p] = acc;
    }
}

extern "C" void kernel_launch(void* const* d_in, const int* in_sizes, int n_in,
                              void* d_out, int out_size, void* d_ws, size_t ws_size,
                              hipStream_t stream) {
    const float* inputs  = (const float*)d_in[0];
    const int*   indices = (const int*)d_in[1];
    const float* embW    = (const float*)d_in[2];
    const float* Wih0    = (const float*)d_in[3];
    const float* Whh0    = (const float*)d_in[4];
    const float* bih0    = (const float*)d_in[5];
    const float* bhh0    = (const float*)d_in[6];
    const float* Wih1    = (const float*)d_in[7];
    const float* Whh1    = (const float*)d_in[8];
    const float* bih1    = (const float*)d_in[9];
    const float* bhh1    = (const float*)d_in[10];
    const float* Wm      = (const float*)d_in[11];
    const float* bm      = (const float*)d_in[12];
    const float* Wv      = (const float*)d_in[13];
    const float* bv      = (const float*)d_in[14];
    const float* Wd      = (const float*)d_in[15];
    const float* bd      = (const float*)d_in[16];
    float* out = (float*)d_out;

    lstm_kernel<<<NN, 512, 0, stream>>>(inputs, Wih0, Whh0, bih0, bhh0,
                                        Wih1, Whh1, bih1, bhh1, out);
    head_kernel<<<TT, 256, 0, stream>>>(embW, indices, Wm, bm, Wv, bv, Wd, bd, out);
}